// Round 8
// baseline (442.774 us; speedup 1.0000x reference)
//
#include <hip/hip_runtime.h>
#include <math.h>

#define NCH     129
#define NT      250
#define DINNER  256
#define DSTATE  16
#define NHEADS  4
#define DPROJ   548   // z(256) + xh(256) + B(16) + C(16) + dt(4)
#define TC      8     // timesteps per chunk; 250 = 31*8 + 2
#define MT      35    // M tiles of 16 (560 >= 548)
#define KS4     4     // K steps of 32 (c=0..127); c=128 via VALU
#define ZR      17    // zxbuf col stride (16 cols + 1 pad)

typedef __attribute__((ext_vector_type(8))) short short8;
typedef __attribute__((ext_vector_type(4))) float f32x4;

template<int N> struct IC { static constexpr int value = N; };

__device__ __forceinline__ float silu_f(float x) { return x / (1.f + __expf(-x)); }

template<int CTRL>
__device__ __forceinline__ float dstep(float v) {
    int t = __builtin_amdgcn_update_dpp(0, __float_as_int(v), CTRL, 0xF, 0xF, true);
    return v + __int_as_float(t);
}
__device__ __forceinline__ float wave_sum63(float v) {
    v = dstep<0xB1>(v);  v = dstep<0x4E>(v);  v = dstep<0x141>(v);
    v = dstep<0x140>(v); v = dstep<0x142>(v); v = dstep<0x143>(v);
    return v;   // lane 63 = total
}
__device__ __forceinline__ float rdlane(float v, int l) {
    return __uint_as_float(__builtin_amdgcn_readlane(__float_as_uint(v), l));
}
__device__ __forceinline__ unsigned short f2bf(float f) {   // RNE
    unsigned u = __float_as_uint(f);
    u += 0x7FFF + ((u >> 16) & 1);
    return (unsigned short)(u >> 16);
}
__device__ __forceinline__ float bf2f(unsigned short h) {
    return __uint_as_float(((unsigned)h) << 16);
}

// ---------- prep: W2t[c][j] = in_proj_w @ mixer_w (fused); bias2[j] ----------
__global__ __launch_bounds__(256) void k_prep_w2(const float* __restrict__ in_proj_w,
                                                 const float* __restrict__ mixer_w,
                                                 const float* __restrict__ mixer_b,
                                                 float* __restrict__ w2t,
                                                 float* __restrict__ bias2) {
    int j = blockIdx.x;
    int c = threadIdx.x;
    if (c < NCH) {
        float acc = 0.f;
        for (int d = 0; d < 128; ++d)
            acc += in_proj_w[j * 128 + d] * mixer_w[d * NCH + c];
        w2t[(size_t)c * DPROJ + j] = acc;
    } else if (c == NCH) {
        float acc = 0.f;
        for (int d = 0; d < 128; ++d)
            acc += in_proj_w[j * 128 + d] * mixer_b[d];
        bias2[j] = acc;
    }
}

// ---------- prep: v[i] = head_w @ out_proj_w ----------
__global__ __launch_bounds__(256) void k_prep_v(const float* __restrict__ head_w,
                                                const float* __restrict__ out_proj_w,
                                                float* __restrict__ v) {
    int i = threadIdx.x;
    float acc = 0.f;
    for (int d = 0; d < 128; ++d)
        acc += head_w[d] * out_proj_w[(size_t)d * DINNER + i];
    v[i] = acc;
}

// ---------- prep: split-bf16 A-frags of W2 (KS4 k-steps, c<128), 16x16x32 layout ----------
__global__ __launch_bounds__(64) void k_prep_frag(const float* __restrict__ w2t,
                                                  unsigned short* __restrict__ ahi,
                                                  unsigned short* __restrict__ alo) {
    int mt = blockIdx.x, ks = blockIdx.y;
    int lane = threadIdx.x;
    int m = mt * 16 + (lane & 15);
    size_t base = (((size_t)(mt * KS4 + ks)) * 64 + lane) * 8;
    for (int i = 0; i < 8; ++i) {
        int k = ks * 32 + (lane >> 4) * 8 + i;   // < 128 always
        float v = (m < DPROJ) ? w2t[(size_t)k * DPROJ + m] : 0.f;
        unsigned short hb = f2bf(v);
        ahi[base + i] = hb;
        alo[base + i] = f2bf(v - bf2f(hb));
    }
}

// ---------- fused: 2 batches/block, 640 thr = 10 waves ----------
// waves 0-3: batch0 channels; waves 4-7: batch1 channels; waves 8,9: aux for b0,b1.
__global__ __launch_bounds__(640, 1) void k_fused(
    const float* __restrict__ x,        // [B,129,250]
    const unsigned short* __restrict__ ahi,
    const unsigned short* __restrict__ alo,
    const float* __restrict__ w2t,      // [129,548] (row 128 used)
    const float* __restrict__ bias2,
    const float* __restrict__ conv_w,
    const float* __restrict__ conv_b,
    const float* __restrict__ dt_bias,
    const float* __restrict__ A_log,
    const float* __restrict__ Dv,
    const float* __restrict__ norm_w,
    const float* __restrict__ vv,
    const float* __restrict__ head_b,
    float* __restrict__ out)
{
    __shared__ short xh[KS4 * 64 * 8];        // bf16-hi of x chunk, MFMA-B fragment order
    __shared__ short xl[KS4 * 64 * 8];        // bf16-lo
    __shared__ float x128buf[2][2][TC];       // c=128 raw, [parity][batch][tt]
    __shared__ float zxbuf[DPROJ * ZR];       // [j][col], col = b*8+tt
    __shared__ float bcbuf[2][TC][32];        // [batch][tt][0..15 B | 16..31 C]
    __shared__ float dtbuf[2][TC][NHEADS];
    __shared__ float dAbuf[2][TC][NHEADS];
    __shared__ float smp[2][2][TC][8];        // [parity][batch][tt][2w(+1)]

    const int b2   = blockIdx.x;
    const int tid  = threadIdx.x;
    const int lane = tid & 63;
    const int wv   = tid >> 6;                // 0..9
    const bool isMain = (wv < 8);
    const int mb   = isMain ? (wv >> 2) : (wv - 8);
    const int p    = ((wv & 3) << 6) | lane;  // main channel (valid if isMain)
    const int q    = lane;
    const int tcol = lane & 15;
    const int quad = lane >> 4;
    const bool isFold = isMain && ((wv & 3) == 0);   // waves 0 (b0) and 4 (b1)

    const float* w128 = w2t + (size_t)128 * DPROJ;

    float bz = 0.f, bx = 0.f, w1z = 0.f, w1x = 0.f;
    float cw0 = 0.f, cw1 = 0.f, cw2 = 0.f, cw3 = 0.f, ccb = 0.f;
    float dtb = 0.f, Ah = 0.f, Dh = 0.f, nv = 0.f;
    if (isMain) {
        bz = bias2[p];          w1z = w128[p];
        bx = bias2[DINNER + p]; w1x = w128[DINNER + p];
        cw0 = conv_w[p * 4 + 0]; cw1 = conv_w[p * 4 + 1];
        cw2 = conv_w[p * 4 + 2]; cw3 = conv_w[p * 4 + 3];
        ccb = conv_b[p];
        Dh = Dv[p >> 6];
        nv = norm_w[p] * vv[p];
    } else if (q < 36) {
        bx  = bias2[2 * DINNER + q];
        w1x = w128[2 * DINNER + q];
        if (q < 32) {
            int ch = DINNER + q;
            cw0 = conv_w[ch * 4 + 0]; cw1 = conv_w[ch * 4 + 1];
            cw2 = conv_w[ch * 4 + 2]; cw3 = conv_w[ch * 4 + 3];
            ccb = conv_b[ch];
        } else {
            int h = q - 32;
            dtb = dt_bias[h];
            Ah  = -expf(A_log[h]);
        }
    }

    float za[TC], xa[TC], hs[DSTATE];
    float c1 = 0.f, c2 = 0.f, c3 = 0.f, outacc = 0.f;
#pragma unroll
    for (int n = 0; n < DSTATE; ++n) hs[n] = 0.f;

    const float* xb_aux = x + ((size_t)2 * b2 + mb) * NCH * NT;  // aux's batch
    const int hh = wv & 3;                                       // head (main)
    float2 pr[9];

    auto load_chunk = [&](int t0, auto Lc) {
        constexpr int L  = decltype(Lc)::value;
        constexpr int HP = (L >= 2) ? L / 2 : 1;
        constexpr int PAIRS = NCH * HP;
#pragma unroll
        for (int k = 0; k * 64 < PAIRS; ++k) {
            int u = lane + 64 * k;
            if (u < PAIRS) {
                int c = u / HP, tp = u - c * HP;
                pr[k] = *(const float2*)(xb_aux + c * NT + t0 + 2 * tp);
            }
        }
    };
    // store into MFMA-B fragment order: elem (k=c, col) -> xh[(ks*64 + quadK*16 + col)*8 + i]
    auto store_chunk = [&](auto Lc, int nxtpar) {
        constexpr int L  = decltype(Lc)::value;
        constexpr int HP = (L >= 2) ? L / 2 : 1;
        constexpr int PAIRS = NCH * HP;
#pragma unroll
        for (int k = 0; k * 64 < PAIRS; ++k) {
            int u = lane + 64 * k;
            if (u < PAIRS) {
                int c = u / HP, tp = u - c * HP;
                float2 v = pr[k];
                if (c < 128) {
                    int base = ((c >> 5) * 64 + ((c >> 3) & 3) * 16) * 8 + (c & 7);
                    int col0 = mb * 8 + 2 * tp;
                    unsigned short h0 = f2bf(v.x), h1 = f2bf(v.y);
                    xh[base + col0 * 8]       = (short)h0;
                    xh[base + (col0 + 1) * 8] = (short)h1;
                    xl[base + col0 * 8]       = (short)f2bf(v.x - bf2f(h0));
                    xl[base + (col0 + 1) * 8] = (short)f2bf(v.y - bf2f(h1));
                } else {
                    x128buf[nxtpar][mb][2 * tp]     = v.x;
                    x128buf[nxtpar][mb][2 * tp + 1] = v.y;
                }
            }
        }
    };

    // prologue: stage chunk 0 (parity 0)
    if (!isMain) { load_chunk(0, IC<TC>{}); store_chunk(IC<TC>{}, 0); }
    __syncthreads();

    auto stage = [&](auto CLc, auto NLc, int s) {
        constexpr int CL = decltype(CLc)::value;
        constexpr int NL = decltype(NLc)::value;
        const int cur = s & 1;

        // ---------------- P1: MFMA GEMM ----------------
        if (isMain) {
            short8 bh[KS4], bl[KS4];
#pragma unroll
            for (int ks = 0; ks < KS4; ++ks) {
                bh[ks] = *(const short8*)&xh[(ks * 64 + lane) * 8];   // conflict-free b128
                bl[ks] = *(const short8*)&xl[(ks * 64 + lane) * 8];
            }
            for (int mt = wv; mt < MT; mt += 8) {
                f32x4 a0 = {0.f, 0.f, 0.f, 0.f};
                f32x4 a1 = {0.f, 0.f, 0.f, 0.f};
#pragma unroll
                for (int ks = 0; ks < KS4; ++ks) {
                    size_t fo = (((size_t)(mt * KS4 + ks)) * 64 + lane) * 8;
                    short8 ah = *(const short8*)(ahi + fo);
                    short8 al = *(const short8*)(alo + fo);
                    a0 = __builtin_amdgcn_mfma_f32_16x16x32_bf16(ah, bh[ks], a0, 0, 0, 0);
                    a1 = __builtin_amdgcn_mfma_f32_16x16x32_bf16(ah, bl[ks], a1, 0, 0, 0);
                    a1 = __builtin_amdgcn_mfma_f32_16x16x32_bf16(al, bh[ks], a1, 0, 0, 0);
                }
#pragma unroll
                for (int r = 0; r < 4; ++r) {
                    int j = mt * 16 + quad * 4 + r;
                    if (j < DPROJ) zxbuf[j * ZR + tcol] = a0[r] + a1[r];
                }
            }
        } else {
            if constexpr (NL > 0) load_chunk((s + 1) * TC, IC<NL>{});
        }
        __syncthreads();   // A: zxbuf ready; xh/xl consumed

        // ---------------- P2a ----------------
        if (isMain) {
            if (isFold && s > 0 && lane < TC) {   // fold prev chunk's partials
                const float* sp = smp[(s - 1) & 1][mb][lane];
                float s1 = sp[0] + sp[2] + sp[4] + sp[6];
                float s2 = sp[1] + sp[3] + sp[5] + sp[7];
                outacc = fmaf(s2, rsqrtf(fmaf(s1, 1.f / DINNER, 1e-5f)), outacc);
            }
#pragma unroll
            for (int tt = 0; tt < CL; ++tt) {
                float xm = x128buf[cur][mb][tt];
                int col = mb * 8 + tt;
                float zraw = zxbuf[p * ZR + col] + bz + w1z * xm;
                float xraw = zxbuf[(DINNER + p) * ZR + col] + bx + w1x * xm;
                float cv = fmaf(cw3, xraw, fmaf(cw2, c1, fmaf(cw1, c2, fmaf(cw0, c3, ccb))));
                c3 = c2; c2 = c1; c1 = xraw;
                xa[tt] = silu_f(cv);
                za[tt] = silu_f(zraw);
            }
        } else {
            if constexpr (NL > 0) store_chunk(IC<NL>{}, (s + 1) & 1);
            if (q < 32) {
#pragma unroll
                for (int tt = 0; tt < CL; ++tt) {
                    float xm = x128buf[cur][mb][tt];
                    float raw = zxbuf[(2 * DINNER + q) * ZR + mb * 8 + tt] + bx + w1x * xm;
                    float cv = fmaf(cw3, raw, fmaf(cw2, c1, fmaf(cw1, c2, fmaf(cw0, c3, ccb))));
                    c3 = c2; c2 = c1; c1 = raw;
                    bcbuf[mb][tt][q] = silu_f(cv);
                }
            } else if (q < 36) {
                int h = q - 32;
#pragma unroll
                for (int tt = 0; tt < CL; ++tt) {
                    float xm = x128buf[cur][mb][tt];
                    float val = zxbuf[(544 + h) * ZR + mb * 8 + tt] + bx + w1x * xm + dtb;
                    float dt = (val > 20.f) ? val : log1pf(expf(val));
                    dtbuf[mb][tt][h] = dt;
                    dAbuf[mb][tt][h] = __expf(dt * Ah);
                }
            }
        }
        __syncthreads();   // B: bc/dt ready; xh/xl restaged

        // ---------------- P2b: scan + DPP reductions ----------------
        if (isMain) {
#pragma unroll
            for (int tt = 0; tt < CL; ++tt) {
                float xv  = xa[tt];
                float g   = za[tt];
                float dtv = dtbuf[mb][tt][hh];
                float dAv = dAbuf[mb][tt][hh];
                float bcv = bcbuf[mb][tt][lane & 31];
                float dx = dtv * xv;
                float y0 = 0.f, y1 = 0.f, y2 = 0.f, y3 = 0.f;
#pragma unroll
                for (int n = 0; n < 4; ++n) {
                    float b0 = rdlane(bcv, n),      cc0 = rdlane(bcv, DSTATE + n);
                    float b1 = rdlane(bcv, 4 + n),  cc1 = rdlane(bcv, DSTATE + 4 + n);
                    float b2v = rdlane(bcv, 8 + n), cc2 = rdlane(bcv, DSTATE + 8 + n);
                    float b3 = rdlane(bcv, 12 + n), cc3 = rdlane(bcv, DSTATE + 12 + n);
                    hs[n]      = fmaf(hs[n],      dAv, dx * b0);  y0 = fmaf(hs[n],      cc0, y0);
                    hs[4 + n]  = fmaf(hs[4 + n],  dAv, dx * b1);  y1 = fmaf(hs[4 + n],  cc1, y1);
                    hs[8 + n]  = fmaf(hs[8 + n],  dAv, dx * b2v); y2 = fmaf(hs[8 + n],  cc2, y2);
                    hs[12 + n] = fmaf(hs[12 + n], dAv, dx * b3);  y3 = fmaf(hs[12 + n], cc3, y3);
                }
                float val = fmaf(Dh, xv, (y0 + y1) + (y2 + y3)) * g;
                float s1 = wave_sum63(val * val);
                float s2 = wave_sum63(val * nv);
                if (lane == 63) {
                    smp[cur][mb][tt][2 * (wv & 3)]     = s1;
                    smp[cur][mb][tt][2 * (wv & 3) + 1] = s2;
                }
            }
        }
        // no barrier: next P1 doesn't touch smp/bcbuf; smp consumed after barrier A
    };

    stage(IC<8>{}, IC<8>{}, 0);
    for (int s = 1; s <= 29; ++s) stage(IC<8>{}, IC<8>{}, s);
    stage(IC<8>{}, IC<2>{}, 30);
    stage(IC<2>{}, IC<0>{}, 31);
    __syncthreads();

    if (isFold) {
        if (lane < 2) {   // fold tail chunk (stage 31, parity 1, CL=2)
            const float* sp = smp[1][mb][lane];
            float s1 = sp[0] + sp[2] + sp[4] + sp[6];
            float s2 = sp[1] + sp[3] + sp[5] + sp[7];
            outacc = fmaf(s2, rsqrtf(fmaf(s1, 1.f / DINNER, 1e-5f)), outacc);
        }
        float tot = wave_sum63(outacc);
        if (lane == 63) out[2 * b2 + mb] = head_b[0] + tot * (1.f / NT);
    }
}

extern "C" void kernel_launch(void* const* d_in, const int* in_sizes, int n_in,
                              void* d_out, int out_size, void* d_ws, size_t ws_size,
                              hipStream_t stream) {
    const float* x         = (const float*)d_in[0];
    const float* mixer_w   = (const float*)d_in[1];
    const float* mixer_b   = (const float*)d_in[2];
    const float* in_proj_w = (const float*)d_in[3];
    const float* conv_w    = (const float*)d_in[4];
    const float* conv_b    = (const float*)d_in[5];
    const float* dt_bias   = (const float*)d_in[6];
    const float* A_log     = (const float*)d_in[7];
    const float* Dp        = (const float*)d_in[8];
    const float* norm_w    = (const float*)d_in[9];
    const float* out_proj_w= (const float*)d_in[10];
    const float* head_w    = (const float*)d_in[11];
    const float* head_b    = (const float*)d_in[12];
    float* out = (float*)d_out;

    int B = in_sizes[0] / (NCH * NT);   // 512

    float* ws    = (float*)d_ws;
    float* w2t   = ws;                          // 129*548 f32
    float* bias2 = w2t + (size_t)NCH * DPROJ;
    float* vvp   = bias2 + DPROJ;
    unsigned short* ahi = (unsigned short*)(vvp + DINNER);       // 35*4*64*8 shorts
    unsigned short* alo = ahi + (size_t)MT * KS4 * 64 * 8;

    k_prep_w2<<<DPROJ, 256, 0, stream>>>(in_proj_w, mixer_w, mixer_b, w2t, bias2);
    k_prep_v<<<1, 256, 0, stream>>>(head_w, out_proj_w, vvp);
    k_prep_frag<<<dim3(MT, KS4), 64, 0, stream>>>(w2t, ahi, alo);
    k_fused<<<B / 2, 640, 0, stream>>>(x, ahi, alo, w2t, bias2, conv_w, conv_b,
                                       dt_bias, A_log, Dp, norm_w, vvp, head_b, out);
}

// Round 9
// 433.316 us; speedup vs baseline: 1.0218x; 1.0218x over previous
//
#include <hip/hip_runtime.h>
#include <math.h>

#define NCH     129
#define NT      250
#define DINNER  256
#define DSTATE  16
#define NHEADS  4
#define DPROJ   548   // z(256) + xh(256) + B(16) + C(16) + dt(4)
#define TC      16    // timesteps per stage; 250 = 15*16 + 10
#define NMT     18    // M tiles of 32 (576 >= 548)
#define NKS     8     // K steps of 16 (c=0..127); c=128 via VALU
#define ZR      33    // zxbuf col stride (32 cols + 1 pad)

typedef __attribute__((ext_vector_type(8)))  short short8;
typedef __attribute__((ext_vector_type(16))) float f32x16;

template<int N> struct IC { static constexpr int value = N; };

__device__ __forceinline__ float silu_f(float x) { return x / (1.f + __expf(-x)); }

template<int CTRL>
__device__ __forceinline__ float dstep(float v) {
    int t = __builtin_amdgcn_update_dpp(0, __float_as_int(v), CTRL, 0xF, 0xF, true);
    return v + __int_as_float(t);
}
__device__ __forceinline__ float wave_sum63(float v) {
    v = dstep<0xB1>(v);  v = dstep<0x4E>(v);  v = dstep<0x141>(v);
    v = dstep<0x140>(v); v = dstep<0x142>(v); v = dstep<0x143>(v);
    return v;   // lane 63 = total
}
__device__ __forceinline__ float rdlane(float v, int l) {
    return __uint_as_float(__builtin_amdgcn_readlane(__float_as_uint(v), l));
}
__device__ __forceinline__ unsigned short f2bf(float f) {   // RNE
    unsigned u = __float_as_uint(f);
    u += 0x7FFF + ((u >> 16) & 1);
    return (unsigned short)(u >> 16);
}
__device__ __forceinline__ float bf2f(unsigned short h) {
    return __uint_as_float(((unsigned)h) << 16);
}

// ---------- single prep kernel, grid = NMT*NKS + 2 ----------
// blocks [0,144): A-fragments of W2 = in_proj_w @ mixer_w (computed directly,
//   split bf16 hi/lo, 32x32x16 layout: A[m=lane&31][k=(lane>>5)*8+i]).
// block 144: bias2[j] (in_proj@mixer_b) and w128[j] (W2 row c=128).
// block 145: vv[i] = head_w @ out_proj_w (exact linear fusion of out_proj+head).
__global__ __launch_bounds__(256) void k_prep(
    const float* __restrict__ in_proj_w,  // [548,128]
    const float* __restrict__ mixer_w,    // [128,129]
    const float* __restrict__ mixer_b,    // [128]
    const float* __restrict__ head_w,     // [1,128]
    const float* __restrict__ out_proj_w, // [128,256]
    unsigned short* __restrict__ ahi,
    unsigned short* __restrict__ alo,
    float* __restrict__ bias2,
    float* __restrict__ w128,
    float* __restrict__ vvp)
{
    int blk = blockIdx.x;
    int t = threadIdx.x;
    if (blk < NMT * NKS) {
        int mt = blk >> 3, ks = blk & 7;
        int lane = t & 63, sub = t >> 6;
        int m = mt * 32 + (lane & 31);
#pragma unroll
        for (int ii = 0; ii < 2; ++ii) {
            int i = sub * 2 + ii;
            int k = ks * 16 + (lane >> 5) * 8 + i;      // < 128
            float acc = 0.f;
            if (m < DPROJ)
                for (int d = 0; d < 128; ++d)
                    acc += in_proj_w[m * 128 + d] * mixer_w[d * NCH + k];
            unsigned short hb = f2bf(acc);
            size_t o = (((size_t)(mt * NKS + ks)) * 64 + lane) * 8 + i;
            ahi[o] = hb;
            alo[o] = f2bf(acc - bf2f(hb));
        }
    } else if (blk == NMT * NKS) {
#pragma unroll
        for (int r = 0; r < 3; ++r) {
            int j = (r == 0) ? t : (r == 1) ? t + 256 : 512 + t;
            if (r == 2 && t >= 36) break;
            float ab = 0.f, aw = 0.f;
            for (int d = 0; d < 128; ++d) {
                float w = in_proj_w[j * 128 + d];
                ab += w * mixer_b[d];
                aw += w * mixer_w[d * NCH + 128];
            }
            bias2[j] = ab;
            w128[j]  = aw;
        }
    } else {
        float acc = 0.f;
        for (int d = 0; d < 128; ++d)
            acc += head_w[d] * out_proj_w[d * DINNER + t];
        vvp[t] = acc;
    }
}

// ---------- fused: 2 batches/block, 512 thr = 8 homogeneous waves ----------
// wave wv: batch mb=wv>>2, channels p = (wv&3)*64 + lane. All waves also stage x.
// waves with (wv&3)==1, lane<36: B/C conv + dt for their batch.
// waves with (wv&3)==0: fold RMS partials, write out.
__global__ __launch_bounds__(512, 1) void k_fused(
    const float* __restrict__ x,        // [B,129,250]
    const unsigned short* __restrict__ ahi,
    const unsigned short* __restrict__ alo,
    const float* __restrict__ bias2,
    const float* __restrict__ w128,
    const float* __restrict__ conv_w,
    const float* __restrict__ conv_b,
    const float* __restrict__ dt_bias,
    const float* __restrict__ A_log,
    const float* __restrict__ Dv,
    const float* __restrict__ norm_w,
    const float* __restrict__ vv,
    const float* __restrict__ head_b,
    float* __restrict__ out)
{
    __shared__ short xh[NKS * 64 * 8];        // bf16-hi x chunk, MFMA-B frag order (8 KB)
    __shared__ short xl[NKS * 64 * 8];        // bf16-lo (8 KB)
    __shared__ float zxbuf[DPROJ * ZR];       // [j][col], col = mb*16+tt (72 KB)
    __shared__ float bcbuf[2][TC][32];        // [batch][tt][0..15 B | 16..31 C]
    __shared__ float dtbuf[2][TC][NHEADS];
    __shared__ float dAbuf[2][TC][NHEADS];
    __shared__ float x128buf[2][2][TC];       // [parity][batch][tt]
    __shared__ float smp[2][2][TC][8];        // [parity][batch][tt][2w(+1)]

    const int b2   = blockIdx.x;
    const int tid  = threadIdx.x;
    const int lane = tid & 63;
    const int wv   = tid >> 6;               // 0..7
    const int mb   = wv >> 2;                // batch within block
    const int wq   = wv & 3;
    const int p    = (wq << 6) | lane;       // channel 0..255
    const bool isBC   = (wq == 1) && (lane < 36);
    const bool isFold = (wq == 0);

    float bz = bias2[p], bx = bias2[DINNER + p];
    float w1z = w128[p], w1x = w128[DINNER + p];
    float cw0 = conv_w[p * 4 + 0], cw1 = conv_w[p * 4 + 1];
    float cw2 = conv_w[p * 4 + 2], cw3 = conv_w[p * 4 + 3];
    float ccb = conv_b[p];
    float Dh  = Dv[wq];
    float nv  = norm_w[p] * vv[p];
    float bxb = 0.f, w1b = 0.f, e0 = 0.f, e1 = 0.f, e2 = 0.f, e3 = 0.f, eb = 0.f;
    float dtb = 0.f, Ah = 0.f;
    if (isBC) {
        bxb = bias2[512 + lane]; w1b = w128[512 + lane];
        if (lane < 32) {
            int ch = DINNER + lane;
            e0 = conv_w[ch * 4 + 0]; e1 = conv_w[ch * 4 + 1];
            e2 = conv_w[ch * 4 + 2]; e3 = conv_w[ch * 4 + 3];
            eb = conv_b[ch];
        } else {
            dtb = dt_bias[lane - 32];
            Ah  = -expf(A_log[lane - 32]);
        }
    }

    float za[TC], xa[TC], hs[DSTATE];
    float c1 = 0.f, c2 = 0.f, c3 = 0.f;      // own conv state
    float g1 = 0.f, g2 = 0.f, g3 = 0.f;      // BC conv state
    float outacc = 0.f;
#pragma unroll
    for (int n = 0; n < DSTATE; ++n) hs[n] = 0.f;

    const float* xbase = x + (size_t)2 * b2 * NCH * NT;
    float2 pr[5];

    auto load_chunk = [&](int t0, auto Lc) {
        constexpr int L  = decltype(Lc)::value;
        constexpr int HP = L / 2;
        constexpr int NP = NCH * HP;
#pragma unroll
        for (int k = 0; k * 512 < 2 * NP; ++k) {
            int g = tid + 512 * k;
            if (g < 2 * NP) {
                int mbx = (g >= NP) ? 1 : 0;
                int rem = g - mbx * NP;
                int c = rem / HP, tp = rem - c * HP;
                pr[k] = *(const float2*)(xbase + (size_t)mbx * NCH * NT + c * NT + t0 + 2 * tp);
            }
        }
    };
    auto scatter_chunk = [&](auto Lc, int par) {
        constexpr int L  = decltype(Lc)::value;
        constexpr int HP = L / 2;
        constexpr int NP = NCH * HP;
#pragma unroll
        for (int k = 0; k * 512 < 2 * NP; ++k) {
            int g = tid + 512 * k;
            if (g < 2 * NP) {
                int mbx = (g >= NP) ? 1 : 0;
                int rem = g - mbx * NP;
                int c = rem / HP, tp = rem - c * HP;
                float2 v = pr[k];
                if (c < 128) {
                    int ks = c >> 4, half = (c >> 3) & 1, i = c & 7;
                    int col = mbx * 16 + 2 * tp;
                    int pos = (ks * 64 + half * 32 + col) * 8 + i;
                    unsigned short h0 = f2bf(v.x), h1 = f2bf(v.y);
                    xh[pos]     = (short)h0;
                    xh[pos + 8] = (short)h1;
                    xl[pos]     = (short)f2bf(v.x - bf2f(h0));
                    xl[pos + 8] = (short)f2bf(v.y - bf2f(h1));
                } else {
                    x128buf[par][mbx][2 * tp]     = v.x;
                    x128buf[par][mbx][2 * tp + 1] = v.y;
                }
            }
        }
    };

    // prologue: stage chunk 0 (parity 0)
    load_chunk(0, IC<TC>{});
    scatter_chunk(IC<TC>{}, 0);
    __syncthreads();

    auto stage = [&](auto CLc, auto NLc, int s) {
        constexpr int CL = decltype(CLc)::value;
        constexpr int NL = decltype(NLc)::value;
        const int cur = s & 1;

        // ---------------- P1: 32x32x16 MFMA GEMM ----------------
        if constexpr (NL > 0) load_chunk((s + 1) * TC, IC<NL>{});
        for (int mt = wv; mt < NMT; mt += 8) {
            f32x16 a0 = {0.f,0.f,0.f,0.f,0.f,0.f,0.f,0.f,0.f,0.f,0.f,0.f,0.f,0.f,0.f,0.f};
            f32x16 a1 = {0.f,0.f,0.f,0.f,0.f,0.f,0.f,0.f,0.f,0.f,0.f,0.f,0.f,0.f,0.f,0.f};
#pragma unroll
            for (int ks = 0; ks < NKS; ++ks) {
                size_t fo = (((size_t)(mt * NKS + ks)) * 64 + lane) * 8;
                short8 ah  = *(const short8*)(ahi + fo);
                short8 al  = *(const short8*)(alo + fo);
                short8 bhv = *(const short8*)&xh[(ks * 64 + lane) * 8];
                short8 blv = *(const short8*)&xl[(ks * 64 + lane) * 8];
                a0 = __builtin_amdgcn_mfma_f32_32x32x16_bf16(ah, bhv, a0, 0, 0, 0);
                a1 = __builtin_amdgcn_mfma_f32_32x32x16_bf16(ah, blv, a1, 0, 0, 0);
                a1 = __builtin_amdgcn_mfma_f32_32x32x16_bf16(al, bhv, a1, 0, 0, 0);
            }
#pragma unroll
            for (int r = 0; r < 16; ++r) {
                int j = mt * 32 + (r & 3) + 8 * (r >> 2) + 4 * (lane >> 5);
                if (j < DPROJ) zxbuf[j * ZR + (lane & 31)] = a0[r] + a1[r];
            }
        }
        __syncthreads();   // A: zxbuf ready; xh/xl consumed

        // ---------------- P2a: scatter next x; fold prev; conv+silu; BC/dt ----
        if constexpr (NL > 0) scatter_chunk(IC<NL>{}, (s + 1) & 1);
        if (isFold && s > 0 && lane < TC) {
            const float* sp = smp[(s - 1) & 1][mb][lane];
            float s1 = sp[0] + sp[2] + sp[4] + sp[6];
            float s2 = sp[1] + sp[3] + sp[5] + sp[7];
            outacc = fmaf(s2, rsqrtf(fmaf(s1, 1.f / DINNER, 1e-5f)), outacc);
        }
#pragma unroll
        for (int tt = 0; tt < CL; ++tt) {
            float xm = x128buf[cur][mb][tt];
            int col = mb * 16 + tt;
            float zraw = zxbuf[p * ZR + col] + bz + w1z * xm;
            float xraw = zxbuf[(DINNER + p) * ZR + col] + bx + w1x * xm;
            float cv = fmaf(cw3, xraw, fmaf(cw2, c1, fmaf(cw1, c2, fmaf(cw0, c3, ccb))));
            c3 = c2; c2 = c1; c1 = xraw;
            xa[tt] = silu_f(cv);
            za[tt] = silu_f(zraw);
        }
        if (isBC) {
            if (lane < 32) {
#pragma unroll
                for (int tt = 0; tt < CL; ++tt) {
                    float xm = x128buf[cur][mb][tt];
                    float raw = zxbuf[(512 + lane) * ZR + mb * 16 + tt] + bxb + w1b * xm;
                    float cv = fmaf(e3, raw, fmaf(e2, g1, fmaf(e1, g2, fmaf(e0, g3, eb))));
                    g3 = g2; g2 = g1; g1 = raw;
                    bcbuf[mb][tt][lane] = silu_f(cv);
                }
            } else {
                int h = lane - 32;
#pragma unroll
                for (int tt = 0; tt < CL; ++tt) {
                    float xm = x128buf[cur][mb][tt];
                    float val = zxbuf[(544 + h) * ZR + mb * 16 + tt] + bxb + w1b * xm + dtb;
                    float dt = (val > 20.f) ? val : log1pf(expf(val));
                    dtbuf[mb][tt][h] = dt;
                    dAbuf[mb][tt][h] = __expf(dt * Ah);
                }
            }
        }
        __syncthreads();   // B: bc/dt ready; xh/xl restaged for next stage

        // ---------------- P2b: scan + DPP reductions ----------------
#pragma unroll
        for (int tt = 0; tt < CL; ++tt) {
            float xv  = xa[tt];
            float g   = za[tt];
            float dtv = dtbuf[mb][tt][wq];
            float dAv = dAbuf[mb][tt][wq];
            float bcv = bcbuf[mb][tt][lane & 31];
            float dx = dtv * xv;
            float y0 = 0.f, y1 = 0.f, y2 = 0.f, y3 = 0.f;
#pragma unroll
            for (int n = 0; n < 4; ++n) {
                float b0 = rdlane(bcv, n),      cc0 = rdlane(bcv, DSTATE + n);
                float b1 = rdlane(bcv, 4 + n),  cc1 = rdlane(bcv, DSTATE + 4 + n);
                float b2v = rdlane(bcv, 8 + n), cc2 = rdlane(bcv, DSTATE + 8 + n);
                float b3 = rdlane(bcv, 12 + n), cc3 = rdlane(bcv, DSTATE + 12 + n);
                hs[n]      = fmaf(hs[n],      dAv, dx * b0);  y0 = fmaf(hs[n],      cc0, y0);
                hs[4 + n]  = fmaf(hs[4 + n],  dAv, dx * b1);  y1 = fmaf(hs[4 + n],  cc1, y1);
                hs[8 + n]  = fmaf(hs[8 + n],  dAv, dx * b2v); y2 = fmaf(hs[8 + n],  cc2, y2);
                hs[12 + n] = fmaf(hs[12 + n], dAv, dx * b3);  y3 = fmaf(hs[12 + n], cc3, y3);
            }
            float val = fmaf(Dh, xv, (y0 + y1) + (y2 + y3)) * g;
            float s1 = wave_sum63(val * val);
            float s2 = wave_sum63(val * nv);
            if (lane == 63) {
                smp[cur][mb][tt][2 * wq]     = s1;
                smp[cur][mb][tt][2 * wq + 1] = s2;
            }
        }
        // no barrier: next P1 writes zxbuf (readers done pre-B) and reads xh/xl
        // (written pre-B); smp[cur] is read only after next barrier A.
    };

    for (int s = 0; s <= 13; ++s) stage(IC<16>{}, IC<16>{}, s);
    stage(IC<16>{}, IC<10>{}, 14);
    stage(IC<10>{}, IC<0>{},  15);
    __syncthreads();

    if (isFold) {
        if (lane < 10) {   // fold tail chunk (stage 15, parity 1, CL=10)
            const float* sp = smp[1][mb][lane];
            float s1 = sp[0] + sp[2] + sp[4] + sp[6];
            float s2 = sp[1] + sp[3] + sp[5] + sp[7];
            outacc = fmaf(s2, rsqrtf(fmaf(s1, 1.f / DINNER, 1e-5f)), outacc);
        }
        float tot = wave_sum63(outacc);
        if (lane == 63) out[2 * b2 + mb] = head_b[0] + tot * (1.f / NT);
    }
}

extern "C" void kernel_launch(void* const* d_in, const int* in_sizes, int n_in,
                              void* d_out, int out_size, void* d_ws, size_t ws_size,
                              hipStream_t stream) {
    const float* x         = (const float*)d_in[0];
    const float* mixer_w   = (const float*)d_in[1];
    const float* mixer_b   = (const float*)d_in[2];
    const float* in_proj_w = (const float*)d_in[3];
    const float* conv_w    = (const float*)d_in[4];
    const float* conv_b    = (const float*)d_in[5];
    const float* dt_bias   = (const float*)d_in[6];
    const float* A_log     = (const float*)d_in[7];
    const float* Dp        = (const float*)d_in[8];
    const float* norm_w    = (const float*)d_in[9];
    const float* out_proj_w= (const float*)d_in[10];
    const float* head_w    = (const float*)d_in[11];
    const float* head_b    = (const float*)d_in[12];
    float* out = (float*)d_out;

    int B = in_sizes[0] / (NCH * NT);   // 512

    const size_t FRAG = (size_t)NMT * NKS * 64 * 8;   // shorts per matrix
    unsigned short* ahi = (unsigned short*)d_ws;
    unsigned short* alo = ahi + FRAG;
    float* bias2 = (float*)(alo + FRAG);
    float* w128  = bias2 + DPROJ;
    float* vvp   = w128 + DPROJ;

    k_prep<<<NMT * NKS + 2, 256, 0, stream>>>(in_proj_w, mixer_w, mixer_b,
                                              head_w, out_proj_w,
                                              ahi, alo, bias2, w128, vvp);
    k_fused<<<B / 2, 512, 0, stream>>>(x, ahi, alo, bias2, w128, conv_w, conv_b,
                                       dt_bias, A_log, Dp, norm_w, vvp, head_b, out);
}